// Round 4
// baseline (227.634 us; speedup 1.0000x reference)
//
#include <hip/hip_runtime.h>

// N3Tree vertical query, N=2, DATA_DIM=4, DEPTH=7 (8 levels).
// Fully-refined tree -> node ids are arithmetic (no child[] reads), all 8
// data-gather addresses computed up front (MLP=8).
//
// Cache-policy hints:
//  - Levels 6,7 (33.5 MB / 268 MB arrays) have ~0 L2 reuse: non-temporal
//    loads so they don't evict the L2-resident levels 0-5 (4.7 MB).
//  - Output store non-temporal: no write-allocate of 64 MB of output in L2.
// Accumulation order unchanged -> bit-identical output.
//
// Note: __builtin_nontemporal_* requires native clang vector types, not
// HIP_vector_type -> use ext_vector_type(4) alias.

typedef float vfloat4 __attribute__((ext_vector_type(4)));

__global__ __launch_bounds__(256) void n3tree_query(
    const float* __restrict__ data,     // (M, 2,2,2, 4) -> M*32 floats
    const float* __restrict__ indices,  // (Q, 3)
    float*       __restrict__ out,      // (Q, 4)
    int nq)
{
    int q = blockIdx.x * blockDim.x + threadIdx.x;
    if (q >= nq) return;

    float ix = indices[3 * (size_t)q + 0];
    float iy = indices[3 * (size_t)q + 1];
    float iz = indices[3 * (size_t)q + 2];

    // offsets[l] = sum_{k<l} 8^k  (start index of level l in node array)
    constexpr int offs[8] = {0, 1, 9, 73, 585, 4681, 37449, 299593};

    // Phase 1: pure arithmetic — derive all 8 gather addresses.
    size_t addr[8];
    int p = 0;  // octant path index within current level
    #pragma unroll
    for (int l = 0; l < 8; ++l) {
        int cx = (int)(ix * 2.0f); cx = cx < 0 ? 0 : (cx > 1 ? 1 : cx);
        int cy = (int)(iy * 2.0f); cy = cy < 0 ? 0 : (cy > 1 ? 1 : cy);
        int cz = (int)(iz * 2.0f); cz = cz < 0 ? 0 : (cz > 1 ? 1 : cz);
        int cidx = (cx << 2) | (cy << 1) | cz;

        int node = offs[l] + p;
        addr[l] = ((size_t)node << 5) + ((size_t)cidx << 2);

        p = (p << 3) + cidx;
        ix = ix * 2.0f - (float)cx;
        iy = iy * 2.0f - (float)cy;
        iz = iz * 2.0f - (float)cz;
    }

    // Phase 2: issue all 8 independent float4 gathers.
    // Levels 0-5: normal (cacheable, L2-resident arrays).
    // Levels 6-7: non-temporal (streaming; no L2 reuse to protect).
    vfloat4 v[8];
    #pragma unroll
    for (int l = 0; l < 6; ++l)
        v[l] = *reinterpret_cast<const vfloat4*>(data + addr[l]);
    v[6] = __builtin_nontemporal_load(
               reinterpret_cast<const vfloat4*>(data + addr[6]));
    v[7] = __builtin_nontemporal_load(
               reinterpret_cast<const vfloat4*>(data + addr[7]));

    // Phase 3: accumulate in reference order.
    float ax = 0.f, ay = 0.f, az = 0.f, aw = 0.f;
    #pragma unroll
    for (int l = 0; l < 8; ++l) {
        ax += v[l].x; ay += v[l].y; az += v[l].z; aw += v[l].w;
    }

    vfloat4 r; r.x = ax; r.y = ay; r.z = az; r.w = aw;
    __builtin_nontemporal_store(r, reinterpret_cast<vfloat4*>(out) + q);
}

extern "C" void kernel_launch(void* const* d_in, const int* in_sizes, int n_in,
                              void* d_out, int out_size, void* d_ws, size_t ws_size,
                              hipStream_t stream) {
    const float* data    = (const float*)d_in[0];
    const float* indices = (const float*)d_in[2];
    float*       out     = (float*)d_out;

    int nq = in_sizes[2] / 3;           // Q = 4,000,000
    const int block = 256;
    const int grid  = (nq + block - 1) / block;

    n3tree_query<<<grid, block, 0, stream>>>(data, indices, out, nq);
}

// Round 5
// 206.439 us; speedup vs baseline: 1.1027x; 1.1027x over previous
//
#include <hip/hip_runtime.h>

// N3Tree vertical query, N=2, DATA_DIM=4, DEPTH=7 (8 levels).
// Fully-refined tree -> node ids are arithmetic (no child[] reads), all 8
// data-gather addresses computed up front (MLP=8).
//
// Round-5 change: nt ONLY on the level-7 gather.
//  - Round-4 showed nt kills cross-replay L3 residency (FETCH -105MB but
//    EA throughput -18%): nt on L6 (33.5MB, 7.6 touches/line) and on the
//    store were net-negative. L7 (268MB, ~1 touch/line, > L3 anyway) is
//    the only justified nt site: protects L2 from the biggest stream.
// Accumulation order unchanged -> bit-identical output.

typedef float vfloat4 __attribute__((ext_vector_type(4)));

__global__ __launch_bounds__(256) void n3tree_query(
    const float* __restrict__ data,     // (M, 2,2,2, 4) -> M*32 floats
    const float* __restrict__ indices,  // (Q, 3)
    float*       __restrict__ out,      // (Q, 4)
    int nq)
{
    int q = blockIdx.x * blockDim.x + threadIdx.x;
    if (q >= nq) return;

    float ix = indices[3 * (size_t)q + 0];
    float iy = indices[3 * (size_t)q + 1];
    float iz = indices[3 * (size_t)q + 2];

    // offsets[l] = sum_{k<l} 8^k  (start index of level l in node array)
    constexpr int offs[8] = {0, 1, 9, 73, 585, 4681, 37449, 299593};

    // Phase 1: pure arithmetic — derive all 8 gather addresses.
    size_t addr[8];
    int p = 0;  // octant path index within current level
    #pragma unroll
    for (int l = 0; l < 8; ++l) {
        int cx = (int)(ix * 2.0f); cx = cx < 0 ? 0 : (cx > 1 ? 1 : cx);
        int cy = (int)(iy * 2.0f); cy = cy < 0 ? 0 : (cy > 1 ? 1 : cy);
        int cz = (int)(iz * 2.0f); cz = cz < 0 ? 0 : (cz > 1 ? 1 : cz);
        int cidx = (cx << 2) | (cy << 1) | cz;

        int node = offs[l] + p;
        addr[l] = ((size_t)node << 5) + ((size_t)cidx << 2);

        p = (p << 3) + cidx;
        ix = ix * 2.0f - (float)cx;
        iy = iy * 2.0f - (float)cy;
        iz = iz * 2.0f - (float)cz;
    }

    // Phase 2: issue all 8 independent float4 gathers.
    // Levels 0-6: normal (L2/L3-cacheable).
    // Level  7:   non-temporal (268MB stream, ~1 touch/line).
    vfloat4 v[8];
    #pragma unroll
    for (int l = 0; l < 7; ++l)
        v[l] = *reinterpret_cast<const vfloat4*>(data + addr[l]);
    v[7] = __builtin_nontemporal_load(
               reinterpret_cast<const vfloat4*>(data + addr[7]));

    // Phase 3: accumulate in reference order.
    float ax = 0.f, ay = 0.f, az = 0.f, aw = 0.f;
    #pragma unroll
    for (int l = 0; l < 8; ++l) {
        ax += v[l].x; ay += v[l].y; az += v[l].z; aw += v[l].w;
    }

    vfloat4 r; r.x = ax; r.y = ay; r.z = az; r.w = aw;
    *(reinterpret_cast<vfloat4*>(out) + q) = r;
}

extern "C" void kernel_launch(void* const* d_in, const int* in_sizes, int n_in,
                              void* d_out, int out_size, void* d_ws, size_t ws_size,
                              hipStream_t stream) {
    const float* data    = (const float*)d_in[0];
    const float* indices = (const float*)d_in[2];
    float*       out     = (float*)d_out;

    int nq = in_sizes[2] / 3;           // Q = 4,000,000
    const int block = 256;
    const int grid  = (nq + block - 1) / block;

    n3tree_query<<<grid, block, 0, stream>>>(data, indices, out, nq);
}

// Round 6
// 204.645 us; speedup vs baseline: 1.1123x; 1.0088x over previous
//
#include <hip/hip_runtime.h>

// N3Tree vertical query, N=2, DATA_DIM=4, DEPTH=7 (8 levels).
// Fully-refined tree -> node ids are arithmetic (no child[] reads), all 8
// data-gather addresses computed up front (MLP=8).
//
// Cache policy (r6): nt exactly where reuse == 0, cached where reuse > 0.
//  - L7 gather (268MB, ~1 touch/line): nt               [r5: +3.4% win]
//  - indices (48MB stream, 1 touch):   nt               [new]
//  - output  (64MB, write-once):       nt store         [new]
//  - L0-L6 (reused; L6 = 7.6 touches/line): normal      [r4 showed nt here -18%]
// Accumulation order unchanged -> bit-identical output.

typedef float vfloat4 __attribute__((ext_vector_type(4)));

__global__ __launch_bounds__(256) void n3tree_query(
    const float* __restrict__ data,     // (M, 2,2,2, 4) -> M*32 floats
    const float* __restrict__ indices,  // (Q, 3)
    float*       __restrict__ out,      // (Q, 4)
    int nq)
{
    int q = blockIdx.x * blockDim.x + threadIdx.x;
    if (q >= nq) return;

    float ix = __builtin_nontemporal_load(indices + 3 * (size_t)q + 0);
    float iy = __builtin_nontemporal_load(indices + 3 * (size_t)q + 1);
    float iz = __builtin_nontemporal_load(indices + 3 * (size_t)q + 2);

    // offsets[l] = sum_{k<l} 8^k  (start index of level l in node array)
    constexpr int offs[8] = {0, 1, 9, 73, 585, 4681, 37449, 299593};

    // Phase 1: pure arithmetic — derive all 8 gather addresses.
    size_t addr[8];
    int p = 0;  // octant path index within current level
    #pragma unroll
    for (int l = 0; l < 8; ++l) {
        int cx = (int)(ix * 2.0f); cx = cx < 0 ? 0 : (cx > 1 ? 1 : cx);
        int cy = (int)(iy * 2.0f); cy = cy < 0 ? 0 : (cy > 1 ? 1 : cy);
        int cz = (int)(iz * 2.0f); cz = cz < 0 ? 0 : (cz > 1 ? 1 : cz);
        int cidx = (cx << 2) | (cy << 1) | cz;

        int node = offs[l] + p;
        addr[l] = ((size_t)node << 5) + ((size_t)cidx << 2);

        p = (p << 3) + cidx;
        ix = ix * 2.0f - (float)cx;
        iy = iy * 2.0f - (float)cy;
        iz = iz * 2.0f - (float)cz;
    }

    // Phase 2: issue all 8 independent float4 gathers.
    // Levels 0-6: normal (L2/L3-cacheable, reused).
    // Level  7:   non-temporal (268MB stream, ~1 touch/line).
    vfloat4 v[8];
    #pragma unroll
    for (int l = 0; l < 7; ++l)
        v[l] = *reinterpret_cast<const vfloat4*>(data + addr[l]);
    v[7] = __builtin_nontemporal_load(
               reinterpret_cast<const vfloat4*>(data + addr[7]));

    // Phase 3: accumulate in reference order.
    float ax = 0.f, ay = 0.f, az = 0.f, aw = 0.f;
    #pragma unroll
    for (int l = 0; l < 8; ++l) {
        ax += v[l].x; ay += v[l].y; az += v[l].z; aw += v[l].w;
    }

    vfloat4 r; r.x = ax; r.y = ay; r.z = az; r.w = aw;
    __builtin_nontemporal_store(r, reinterpret_cast<vfloat4*>(out) + q);
}

extern "C" void kernel_launch(void* const* d_in, const int* in_sizes, int n_in,
                              void* d_out, int out_size, void* d_ws, size_t ws_size,
                              hipStream_t stream) {
    const float* data    = (const float*)d_in[0];
    const float* indices = (const float*)d_in[2];
    float*       out     = (float*)d_out;

    int nq = in_sizes[2] / 3;           // Q = 4,000,000
    const int block = 256;
    const int grid  = (nq + block - 1) / block;

    n3tree_query<<<grid, block, 0, stream>>>(data, indices, out, nq);
}